// Round 10
// baseline (169.868 us; speedup 1.0000x reference)
//
#include <hip/hip_runtime.h>

#define BINS 64
#define ROWS 192                  // 3 ch * 64 bins (per tensor)
#define HC   384                  // 2 tensors * ROWS
#define BLOCK 1024
#define WPB 16                    // waves per block
#define GRID 512
#define PER 12288                 // vectors per block slab = nvec/GRID
#define ITERS 12                  // PER/BLOCK, exact
// LDS main hist: [ch][bin][lane] u32, pred count in low16, targ in high16
#define LHIST_WORDS (ROWS * 64)   // 12288 words = 48 KiB

typedef float f4 __attribute__((ext_vector_type(4)));

__global__ __launch_bounds__(BLOCK, 8) void hist_fused(
    const f4* __restrict__ pred4,
    const f4* __restrict__ targ4,
    unsigned int* __restrict__ gpart,    // [GRID][HC] private rows
    unsigned int* __restrict__ ticket,   // 1 u32 (never reset; mod-512 trick)
    float* __restrict__ out,
    int nvec)
{
    __shared__ unsigned int lhist[LHIST_WORDS];
    __shared__ unsigned int S[HC];
    __shared__ unsigned int red[2][HC];
    __shared__ int is_last;

    const int tid  = threadIdx.x;
    const int lane = tid & 63;
    const int wave = tid >> 6;

    for (int j = tid; j < LHIST_WORDS; j += BLOCK)
        lhist[j] = 0u;
    __syncthreads();

    // lane-private column: DS access from lane L always hits bank L%32
    // (2-way alias with lane L+32 — free per m136). Zero same-address
    // collisions within a wave; cross-wave collisions resolved by atomic.
    unsigned int* hl = lhist + lane;

    // Branchless bin: clamp((int)(x*64), 0, 63) == reference
    // clip(floor(x*64),0,63) for x in [0,1]; inputs are uniform [0,1)
    // (validated R6-R9, absmax 0). pred adds +1 (low16), targ adds
    // +65536 (high16); max column count <= 1536 so halves never carry.
    #define DO_BIN(x, ch, inc)                                          \
        do {                                                            \
            int _b = (int)((x) * 64.0f);                                \
            _b = _b < 0 ? 0 : (_b > 63 ? 63 : _b);  /* v_med3 */        \
            atomicAdd(&hl[(((ch) << 6) + _b) << 6], (inc));             \
        } while (0)

    #define DO_VEC(p, t, ch)                                            \
        do {                                                            \
            DO_BIN((p).x, ch, 1u);      DO_BIN((p).y, ch, 1u);          \
            DO_BIN((p).z, ch, 1u);      DO_BIN((p).w, ch, 1u);          \
            DO_BIN((t).x, ch, 65536u);  DO_BIN((t).y, ch, 65536u);      \
            DO_BIN((t).z, ch, 65536u);  DO_BIN((t).w, ch, 65536u);      \
        } while (0)

    // bijective XCD swizzle (512 = 8 XCDs * 64): XCD x reads one
    // contiguous 25 MB region -> L2/channel locality (T1).
    const int bid = (int)blockIdx.x;
    const int sw  = ((bid & 7) << 6) + (bid >> 3);

    if (nvec == GRID * PER) {
        const int base = sw * PER + tid;
        #pragma unroll 4
        for (int it = 0; it < ITERS; ++it) {
            const int v = base + it * BLOCK;
            f4 p = pred4[v];
            f4 t = targ4[v];
            // channel = ((4v) >> 18) % 3 = (v >> 16) % 3
            const int c = (v >> 16) % 3;
            DO_VEC(p, t, c);
        }
    } else {
        // generic fallback (never taken for the fixed 32x3x512x512 shape)
        const int per = (nvec + GRID - 1) / GRID;
        const int s0  = sw * per;
        const int end = (s0 + per) < nvec ? (s0 + per) : nvec;
        for (int vv = s0 + tid; vv < end; vv += BLOCK) {
            f4 p = pred4[vv], t = targ4[vv];
            const int c = (vv >> 16) % 3;
            DO_VEC(p, t, c);
        }
    }
    #undef DO_VEC
    #undef DO_BIN

    __syncthreads();

    // flush stage 1: row r = ch*64+bin; one wave per row chunk reads its 64
    // lane-columns conflict-free, shuffle-trees both packed halves, lane 0
    // deposits into S[] (pred at r, targ at ROWS+r).
    for (int r = wave; r < ROWS; r += WPB) {
        unsigned int w  = lhist[(r << 6) + lane];
        unsigned int lo = w & 0xFFFFu;   // pred
        unsigned int hi = w >> 16;       // targ
        #pragma unroll
        for (int o = 32; o >= 1; o >>= 1) {
            lo += __shfl_xor(lo, o);
            hi += __shfl_xor(hi, o);
        }
        if (lane == 0) {
            S[r] = lo;
            S[ROWS + r] = hi;
        }
    }
    __syncthreads();

    // flush stage 2: plain coalesced store of this block's private row.
    // No memset needed (rows fully overwritten each call).
    if (tid < HC)
        gpart[bid * HC + tid] = S[tid];

    // threadfence-reduction handoff: release our row, take a ticket.
    // (t+1) % 512 == 0 picks exactly one block regardless of the ticket
    // cell's initial value (0xAA poison) or u32 wraparound -> deterministic.
    __threadfence();
    if (tid == 0) {
        unsigned int t = atomicAdd(ticket, 1u);
        is_last = (((t + 1) & (GRID - 1)) == 0);
    }
    __syncthreads();

    if (!is_last) return;

    // winner: acquire all rows, reduce 512 x 384, compute the loss.
    __threadfence();
    if (tid < 2 * HC) {
        const int h = tid >= HC;             // row half: 0..255 / 256..511
        const int c = tid - h * HC;          // counter 0..383 (coalesced)
        const unsigned int* col = gpart + c;
        unsigned int s = 0u;
        const int r0 = h * (GRID / 2);
        #pragma unroll 8
        for (int r = 0; r < GRID / 2; ++r)
            s += col[(r0 + r) * HC];
        red[h][c] = s;
    }
    __syncthreads();

    if (tid < HC)
        S[tid] = red[0][tid] + red[1][tid];
    __syncthreads();

    if (tid < 64) {
        const float eps = 1e-7f;
        float acc = 0.0f;

        for (int c = 0; c < 3; ++c) {
            float pc = (float)S[c * BINS + lane];
            float tc = (float)S[ROWS + c * BINS + lane];

            // exact fp32 sums: all counts & partial sums are integers < 2^24
            float ps = pc, ts = tc;
            #pragma unroll
            for (int o = 32; o >= 1; o >>= 1) {
                ps += __shfl_xor(ps, o);
                ts += __shfl_xor(ts, o);
            }

            float d = fabsf(pc / (ps + eps) - tc / (ts + eps));
            #pragma unroll
            for (int o = 32; o >= 1; o >>= 1)
                d += __shfl_xor(d, o);

            acc += d / 64.0f;   // mean over bins
        }

        if (lane == 0) out[0] = acc / 3.0f;
    }
}

extern "C" void kernel_launch(void* const* d_in, const int* in_sizes, int n_in,
                              void* d_out, int out_size, void* d_ws, size_t ws_size,
                              hipStream_t stream)
{
    const float* pred = (const float*)d_in[0];
    const float* targ = (const float*)d_in[1];
    float* out = (float*)d_out;

    unsigned int* gpart  = (unsigned int*)d_ws;          // GRID*HC u32 = 768 KiB
    unsigned int* ticket = gpart + (size_t)GRID * HC;    // 1 u32 after rows

    const long long n = (long long)in_sizes[0];   // 32*3*512*512 = 25,165,824
    const int nvec = (int)(n >> 2);               // 6,291,456 = GRID*PER

    hist_fused<<<GRID, BLOCK, 0, stream>>>(
        (const f4*)pred, (const f4*)targ, gpart, ticket, out, nvec);
}